// Round 1
// baseline (438.481 us; speedup 1.0000x reference)
//
#include <hip/hip_runtime.h>
#include <hip/hip_bf16.h>

typedef __hip_bfloat16 bf16;
typedef __bf16 bf16x8 __attribute__((ext_vector_type(8)));
typedef __bf16 bf16x4 __attribute__((ext_vector_type(4)));
typedef float f32x4 __attribute__((ext_vector_type(4)));
typedef float f32x16 __attribute__((ext_vector_type(16)));
typedef unsigned u32x4 __attribute__((ext_vector_type(4)));

static __device__ __forceinline__ f32x4 mfma16(bf16x8 a, bf16x8 b, f32x4 c) {
  return __builtin_amdgcn_mfma_f32_16x16x32_bf16(a, b, c, 0, 0, 0);
}
static __device__ __forceinline__ f32x16 mfma32(bf16x8 a, bf16x8 b, f32x16 c) {
  return __builtin_amdgcn_mfma_f32_32x32x16_bf16(a, b, c, 0, 0, 0);
}
static __device__ __forceinline__ bf16x8 ld8(const bf16* p) {
  return *reinterpret_cast<const bf16x8*>(p);
}
static __device__ __forceinline__ float toF(float v) { return v; }
static __device__ __forceinline__ float toF(bf16 v) { return __bfloat162float(v); }
static __device__ __forceinline__ void stF(float* p, float v) { *p = v; }
static __device__ __forceinline__ void stF(bf16* p, float v) { *p = __float2bfloat16(v); }
// pack two f32 -> one u32 of 2 bf16 (elem0 in low 16)
static __device__ __forceinline__ unsigned pk2(float lo, float hi) {
  unsigned a = __bfloat16_as_ushort(__float2bfloat16(lo));
  unsigned b = __bfloat16_as_ushort(__float2bfloat16(hi));
  return (b << 16) | a;
}

typedef __attribute__((address_space(1))) void gvoid;
typedef __attribute__((address_space(3))) void lvoid;
static __device__ __forceinline__ void gl2lds16(const bf16* g, bf16* l) {
  __builtin_amdgcn_global_load_lds((gvoid*)g, (lvoid*)l, 16, 0, 0);
}

// ---------------- fp32 -> bf16 elementwise ----------------
__global__ __launch_bounds__(256) void cvt_kernel(const float* __restrict__ in,
                                                  bf16* __restrict__ out) {
  long i = (long)blockIdx.x * 256 + threadIdx.x;
  float4 v = reinterpret_cast<const float4*>(in)[i];
  bf16x4 o;
  o[0] = __float2bfloat16(v.x); o[1] = __float2bfloat16(v.y);
  o[2] = __float2bfloat16(v.z); o[3] = __float2bfloat16(v.w);
  reinterpret_cast<bf16x4*>(out)[i] = o;
}

// ---------------- ALL weight transposes in ONE dispatch ----------------
__global__ void prep_weights(const float* __restrict__ Wq, const float* __restrict__ Wk,
                             const float* __restrict__ Wv, const float* __restrict__ Wo,
                             const float* __restrict__ W1, const float* __restrict__ W2,
                             bf16* __restrict__ Wtqkv, bf16* __restrict__ WtO,
                             bf16* __restrict__ Wt1, bf16* __restrict__ Wt2) {
  int id = blockIdx.x;
  const float* in;
  bf16* out;
  int K, N, n0, k0;
  if (id < 1024) {
    int which = id >> 8, t = id & 255;
    K = 512; N = 512;
    n0 = (t & 15) * 32; k0 = (t >> 4) * 32;
    if (which == 0)      { in = Wq; out = Wtqkv; }
    else if (which == 1) { in = Wk; out = Wtqkv + (size_t)512 * 512; }
    else if (which == 2) { in = Wv; out = Wtqkv + (size_t)1024 * 512; }
    else                 { in = Wo; out = WtO; }
  } else if (id < 2048) {
    int t = id - 1024;
    in = W1; out = Wt1; K = 512; N = 2048;
    n0 = (t & 63) * 32; k0 = (t >> 6) * 32;
  } else {
    int t = id - 2048;
    in = W2; out = Wt2; K = 2048; N = 512;
    n0 = (t & 15) * 32; k0 = (t >> 4) * 32;
  }
  __shared__ float tile[32][33];
  int tx = threadIdx.x, ty = threadIdx.y;
#pragma unroll
  for (int j = 0; j < 32; j += 8)
    tile[ty + j][tx] = in[(long)(k0 + ty + j) * N + n0 + tx];
  __syncthreads();
#pragma unroll
  for (int j = 0; j < 32; j += 8)
    out[(long)(n0 + ty + j) * K + k0 + tx] = __float2bfloat16(tile[tx][ty + j]);
}

// ---------------- MFMA GEMM, dbuf single-barrier K-loop, XCD swizzle ----------------
template <int MODE>
__global__ __launch_bounds__(256) void gemm_kernel(
    const bf16* __restrict__ A, const bf16* __restrict__ Wt,
    const float* __restrict__ b0, const float* __restrict__ b1_,
    const float* __restrict__ b2_, bf16* C0, bf16* C1, bf16* C2,
    int K, int ldc, int mmask, int mshift) {
  __shared__ alignas(16) bf16 As[2][128 * 32];
  __shared__ alignas(16) bf16 Bs[2][128 * 32];
  const int tid = threadIdx.x;
  const int wave = tid >> 6, lane = tid & 63;
  const int lr = lane & 15, lq = lane >> 4;
  const int L = blockIdx.x;
  const int m0 = (L & mmask) * 128, n0 = (L >> mshift) * 128;
  const int wm = (wave >> 1) * 64, wn = (wave & 1) * 64;

  const int srow0 = (wave * 2) * 16 + (lane >> 2);
  const int srow1 = (wave * 2 + 1) * 16 + (lane >> 2);
  const int scol = (lane & 3) * 8;
  const bf16* Ag0 = A + (long)(m0 + srow0) * K + scol;
  const bf16* Ag1 = A + (long)(m0 + srow1) * K + scol;
  const bf16* Bg0 = Wt + (long)(n0 + srow0) * K + scol;
  const bf16* Bg1 = Wt + (long)(n0 + srow1) * K + scol;
  const int so0 = (wave * 2) * 16 * 32;
  const int so1 = (wave * 2 + 1) * 16 * 32;

  f32x4 acc[4][4] = {};

  gl2lds16(Ag0, &As[0][so0]);
  gl2lds16(Ag1, &As[0][so1]);
  gl2lds16(Bg0, &Bs[0][so0]);
  gl2lds16(Bg1, &Bs[0][so1]);
  __syncthreads();

  int p = 0;
  for (int k0 = 0; k0 < K; k0 += 32) {
    int kn = k0 + 32;
    if (kn < K) {  // block-uniform
      gl2lds16(Ag0 + kn, &As[p ^ 1][so0]);
      gl2lds16(Ag1 + kn, &As[p ^ 1][so1]);
      gl2lds16(Bg0 + kn, &Bs[p ^ 1][so0]);
      gl2lds16(Bg1 + kn, &Bs[p ^ 1][so1]);
    }
    bf16x8 af[4], bfr[4];
#pragma unroll
    for (int i = 0; i < 4; ++i) af[i] = ld8(&As[p][(wm + i * 16 + lr) * 32 + lq * 8]);
#pragma unroll
    for (int j = 0; j < 4; ++j) bfr[j] = ld8(&Bs[p][(wn + j * 16 + lr) * 32 + lq * 8]);
#pragma unroll
    for (int i = 0; i < 4; ++i)
#pragma unroll
      for (int j = 0; j < 4; ++j) acc[i][j] = mfma16(af[i], bfr[j], acc[i][j]);
    __syncthreads();  // drains vmcnt: buf p^1 ready; readers of buf p done
    p ^= 1;
  }

  const float* bias = b0;
  bf16* C = C0;
  int cb = n0;
  bool vmode = false;
  if (MODE == 2) {
    if (n0 >= 1024)     { bias = b2_; C = C2; cb = n0 - 1024; vmode = true; }
    else if (n0 >= 512) { bias = b1_; C = C1; cb = n0 - 512; }
  }

#pragma unroll
  for (int i = 0; i < 4; ++i) {
#pragma unroll
    for (int j = 0; j < 4; ++j) {
      int col = cb + wn + j * 16 + lr;
      float bv = bias[col];
#pragma unroll
      for (int rr = 0; rr < 4; ++rr) {
        int row = m0 + wm + i * 16 + lq * 4 + rr;
        float v = acc[i][j][rr] + bv;
        if (MODE == 1) v = 0.5f * v * (1.0f + erff(v * 0.70710678118654752f));
        if (MODE == 2 && vmode) {
          int hh = col >> 6, e = col & 63;
          int bb = row >> 10, tok = row & 1023;
          C[(((long)((bb * 8 + hh) * 64 + e)) << 10) + tok] = __float2bfloat16(v);
        } else {
          C[(long)row * ldc + col] = __float2bfloat16(v);
        }
      }
    }
  }
}

// ---------------- attention: 32x32x16 MFMA, fully in-register softmax ----------------
// One wave owns 32 q-rows x all 1024 keys for one (b,h). No P-LDS, no split-K.
// QK^T: S = mfma32(Kfrag, Qfrag) -> lane holds col q=lane&31, 16 key-rows.
// P fragments for PV built in-register: cvt_pk pairs + 4x permlane32_swap.
// PV: O = mfma32(Pfrag, Vtfrag) -> col e=lane&31, row q (same reg map).
// l-sum: fp32 adds on in-register p + shfl_xor(32); transpose via 512B LDS.
// Grid 1024 = 8 sub-blocks x 128 (b,h); bh in low bits -> same-XCD L2 reuse of K/V.
__global__ __launch_bounds__(256, 4) void attn32(
    const bf16* __restrict__ Q, const bf16* __restrict__ Km,
    const bf16* __restrict__ Vt, bf16* __restrict__ O) {
  __shared__ alignas(16) float lred[4][32];
  const int tid = threadIdx.x;
  const int wave = tid >> 6, lane = tid & 63;
  const int l31 = lane & 31, lh = lane >> 5;
  const int bi = blockIdx.x;
  const int bh = bi & 127;                 // stride-128 groups: same XCD
  const int qt = (bi >> 7) * 4 + wave;     // 0..31
  const int h = bh & 7, b = bh >> 3;
  const int q0 = qt * 32;
  const float Cc = 0.18033688011112042f;   // (1/8)*log2(e)

  // Q fragment (B-operand): col q = l31, K-rows = E slice lh*8..+7, per et*16
  bf16x8 qf[4];
  const bf16* qp = Q + (long)(b * 1024 + q0 + l31) * 512 + h * 64 + lh * 8;
#pragma unroll
  for (int et = 0; et < 4; ++et) qf[et] = ld8(qp + et * 16);

  const bf16* kpt = Km + (long)(b * 1024 + l31) * 512 + h * 64 + lh * 8;
  const bf16* vp0 = Vt + ((long)((b * 8 + h) * 64 + l31)) * 1024 + lh * 8;
  const bf16* vp1 = vp0 + (long)32 * 1024;

  f32x16 oacc[2] = {};
  float lsum = 0.f;

  for (int t = 0; t < 32; ++t) {
    bf16x8 kf[4], vf0a, vf0b, vf1a, vf1b;
#pragma unroll
    for (int et = 0; et < 4; ++et) kf[et] = ld8(kpt + et * 16);
    vf0a = ld8(vp0);      // e-tile 0, keys lh*8..(+16 for ks=1)
    vf0b = ld8(vp0 + 16);
    vf1a = ld8(vp1);
    vf1b = ld8(vp1 + 16);

    f32x16 s = {};
#pragma unroll
    for (int et = 0; et < 4; ++et) s = mfma32(kf[et], qf[et], s);

    float pr[16];
#pragma unroll
    for (int r = 0; r < 16; ++r) { pr[r] = exp2f(s[r] * Cc); lsum += pr[r]; }

    // pack + half-lane swap -> A-operand P fragments (ascending keys per lane-half)
    unsigned w0 = pk2(pr[0], pr[1]),   w1 = pk2(pr[2], pr[3]);
    unsigned w2 = pk2(pr[4], pr[5]),   w3 = pk2(pr[6], pr[7]);
    unsigned w4 = pk2(pr[8], pr[9]),   w5 = pk2(pr[10], pr[11]);
    unsigned w6 = pk2(pr[12], pr[13]), w7 = pk2(pr[14], pr[15]);
    auto r02 = __builtin_amdgcn_permlane32_swap(w0, w2, false, false);
    auto r13 = __builtin_amdgcn_permlane32_swap(w1, w3, false, false);
    auto r46 = __builtin_amdgcn_permlane32_swap(w4, w6, false, false);
    auto r57 = __builtin_amdgcn_permlane32_swap(w5, w7, false, false);
    u32x4 a0 = {r02[0], r13[0], r02[1], r13[1]};   // keys 0..15 (lo:0-7, hi:8-15)
    u32x4 a1 = {r46[0], r57[0], r46[1], r57[1]};   // keys 16..31
    bf16x8 pf0 = __builtin_bit_cast(bf16x8, a0);
    bf16x8 pf1 = __builtin_bit_cast(bf16x8, a1);

    oacc[0] = mfma32(pf0, vf0a, oacc[0]);
    oacc[1] = mfma32(pf0, vf1a, oacc[1]);
    oacc[0] = mfma32(pf1, vf0b, oacc[0]);
    oacc[1] = mfma32(pf1, vf1b, oacc[1]);

    kpt += 32 * 512;
    vp0 += 32;
    vp1 += 32;
  }

  // total l for q = l31 on every lane (lo half holds keys k%8<4 etc; halves sum)
  lsum += __shfl_xor(lsum, 32);
  if (lh == 0) lred[wave][l31] = lsum;
  __syncthreads();

  float linv[16];
#pragma unroll
  for (int g = 0; g < 4; ++g) {
    f32x4 lvv = *(const f32x4*)&lred[wave][g * 8 + 4 * lh];
#pragma unroll
    for (int j = 0; j < 4; ++j) linv[g * 4 + j] = 1.f / lvv[j];
  }

  const long rowbase = (long)(b * 1024 + q0);
#pragma unroll
  for (int et = 0; et < 2; ++et) {
    bf16* obase = O + rowbase * 512 + h * 64 + et * 32 + l31;
#pragma unroll
    for (int r = 0; r < 16; ++r) {
      int q = (r & 3) + 8 * (r >> 2) + 4 * lh;
      obase[(long)q * 512] = __float2bfloat16(oacc[et][r] * linv[r]);
    }
  }
}

// ---------------- fused residual + LayerNorm over D=512 ----------------
template <typename TX, typename TO>
__global__ __launch_bounds__(256) void add_ln_kernel(
    const TX* __restrict__ X, const bf16* __restrict__ Y,
    const float* __restrict__ g, const float* __restrict__ bb,
    TO* __restrict__ out) {
  const int row = blockIdx.x, t = threadIdx.x;
  __shared__ float s1[4], s2[4];
  long base = (long)row * 512;
  float v0 = toF(X[base + t]) + toF(Y[base + t]);
  float v1 = toF(X[base + 256 + t]) + toF(Y[base + 256 + t]);
  float s = v0 + v1, q = v0 * v0 + v1 * v1;
#pragma unroll
  for (int o = 32; o > 0; o >>= 1) {
    s += __shfl_down(s, o);
    q += __shfl_down(q, o);
  }
  int wv = t >> 6;
  if ((t & 63) == 0) { s1[wv] = s; s2[wv] = q; }
  __syncthreads();
  float St = s1[0] + s1[1] + s1[2] + s1[3];
  float Qt = s2[0] + s2[1] + s2[2] + s2[3];
  float mean = St * (1.f / 512.f);
  float var = Qt * (1.f / 512.f) - mean * mean;
  float rs = rsqrtf(var + 1e-5f);
  stF(&out[base + t], (v0 - mean) * rs * g[t] + bb[t]);
  stF(&out[base + 256 + t], (v1 - mean) * rs * g[256 + t] + bb[256 + t]);
}

// ---------------- launch ----------------
extern "C" void kernel_launch(void* const* d_in, const int* in_sizes, int n_in,
                              void* d_out, int out_size, void* d_ws, size_t ws_size,
                              hipStream_t stream) {
  const float* x    = (const float*)d_in[0];
  const float* Wq   = (const float*)d_in[1];
  const float* bq   = (const float*)d_in[2];
  const float* Wk   = (const float*)d_in[3];
  const float* bk   = (const float*)d_in[4];
  const float* Wv   = (const float*)d_in[5];
  const float* bv   = (const float*)d_in[6];
  const float* Wo   = (const float*)d_in[7];
  const float* bo   = (const float*)d_in[8];
  const float* ln1g = (const float*)d_in[9];
  const float* ln1b = (const float*)d_in[10];
  const float* W1   = (const float*)d_in[11];
  const float* b1   = (const float*)d_in[12];
  const float* W2   = (const float*)d_in[13];
  const float* b2   = (const float*)d_in[14];
  const float* ln2g = (const float*)d_in[15];
  const float* ln2b = (const float*)d_in[16];
  float* out = (float*)d_out;

  char* ws = (char*)d_ws;
  size_t off = 0;
  auto alloc = [&](size_t bytes) {
    char* p = ws + off;
    off += (bytes + 255) & ~(size_t)255;
    return (bf16*)p;
  };
  bf16* Wtqkv = alloc((size_t)1536 * 512 * 2);
  bf16* WtO   = alloc((size_t)512 * 512 * 2);
  bf16* Wt1   = alloc((size_t)512 * 2048 * 2);
  bf16* Wt2   = alloc((size_t)2048 * 512 * 2);
  const size_t SB = (size_t)16384 * 512 * 2;  // 16 MB

  dim3 tb(32, 8);

  if (ws_size >= (size_t)104 * 1024 * 1024) {
    // [W 6][xb 16 (x bf16 -> ff2)][kb 16 (K -> x1)]
    // [qb 16 (Q -> O -> ff1)][vtb 16 (Vt -> att -> ff1)]
    // [p0 16 (ff1)][p1 16 (ff1)]   (p0/p1 only provide ff1 contiguity now)
    bf16* xb  = alloc(SB);
    bf16* kb  = alloc(SB);
    bf16* qb  = alloc(SB);
    bf16* vtb = alloc(SB);
    bf16* p0  = alloc(SB);
    bf16* p1  = alloc(SB);
    bf16* ff1 = qb;   // 64 MB contiguous qb|vtb|p0|p1
    bf16* ff2 = xb;
    (void)p0; (void)p1;

    cvt_kernel<<<8192, 256, 0, stream>>>(x, xb);
    prep_weights<<<3072, tb, 0, stream>>>(Wq, Wk, Wv, Wo, W1, W2,
                                          Wtqkv, WtO, Wt1, Wt2);
    gemm_kernel<2><<<1536, 256, 0, stream>>>(xb, Wtqkv, bq, bk, bv,
                                             qb, kb, vtb, 512, 512, 127, 7);
    attn32<<<1024, 256, 0, stream>>>(qb, kb, vtb, qb);  // in-place: O -> qb
    gemm_kernel<0><<<512, 256, 0, stream>>>(qb, WtO, bo, nullptr, nullptr,
                                            vtb, nullptr, nullptr, 512, 512, 127, 7);
    add_ln_kernel<bf16, bf16><<<16384, 256, 0, stream>>>(xb, vtb, ln1g, ln1b, kb);
    gemm_kernel<1><<<2048, 256, 0, stream>>>(kb, Wt1, b1, nullptr, nullptr,
                                             ff1, nullptr, nullptr, 512, 2048, 127, 7);
    gemm_kernel<0><<<512, 256, 0, stream>>>(ff1, Wt2, b2, nullptr, nullptr,
                                            ff2, nullptr, nullptr, 2048, 512, 127, 7);
    add_ln_kernel<bf16, float><<<16384, 256, 0, stream>>>(kb, ff2, ln2g, ln2b, out);
  } else {
    // 78 MB fallback
    bf16* xb  = alloc(SB);
    bf16* kb  = alloc(SB);       // K, then x1
    bf16* qb  = alloc(SB);       // Q, then O, then ff1 lo
    bf16* vtb = alloc(SB);       // Vt, then att, then ff1 hi
    bf16* fb  = alloc(SB / 2);   // ff2 half
    bf16* ff1 = qb;              // 32MB contiguous qb+vtb

    cvt_kernel<<<8192, 256, 0, stream>>>(x, xb);
    prep_weights<<<3072, tb, 0, stream>>>(Wq, Wk, Wv, Wo, W1, W2,
                                          Wtqkv, WtO, Wt1, Wt2);
    gemm_kernel<2><<<1536, 256, 0, stream>>>(xb, Wtqkv, bq, bk, bv,
                                             qb, kb, vtb, 512, 512, 127, 7);
    attn32<<<1024, 256, 0, stream>>>(qb, kb, vtb, qb);
    gemm_kernel<0><<<512, 256, 0, stream>>>(qb, WtO, bo, nullptr, nullptr,
                                            vtb, nullptr, nullptr, 512, 512, 127, 7);
    add_ln_kernel<bf16, bf16><<<16384, 256, 0, stream>>>(xb, vtb, ln1g, ln1b, kb);

    for (int hh = 0; hh < 2; ++hh) {
      const bf16* x1h = kb + (size_t)hh * 8192 * 512;
      gemm_kernel<1><<<1024, 256, 0, stream>>>(x1h, Wt1, b1, nullptr, nullptr,
                                               ff1, nullptr, nullptr, 512, 2048, 63, 6);
      gemm_kernel<0><<<256, 256, 0, stream>>>(ff1, Wt2, b2, nullptr, nullptr,
                                              fb, nullptr, nullptr, 2048, 512, 63, 6);
      add_ln_kernel<bf16, float><<<8192, 256, 0, stream>>>(x1h, fb, ln2g, ln2b,
                                                           out + (size_t)hh * 8192 * 512);
    }
  }
}